// Round 11
// baseline (81.676 us; speedup 1.0000x reference)
//
#include <hip/hip_runtime.h>
#include <stdint.h>

#define UNITS  512
#define IN_DIM 1024
#define KCONN  32
#define BATCH  16384

#define BM 64
#define BN 128
#define BK 64
#define NT 256            // 4 waves
#define KS (IN_DIM / BK)  // 16

typedef _Float16 f16x8 __attribute__((ext_vector_type(8)));
typedef __fp16   hf16x2 __attribute__((ext_vector_type(2)));
typedef float    f32x4 __attribute__((ext_vector_type(4)));

// ---------------- Kernel 1: top-32 per unit -> dense f16 W' row ----------------
// (r8-r10-verified DPP selection.) Bt[u][i] = (f16)W[u,i] at selected i, else 0.

template <int CTRL, int RM>
__device__ __forceinline__ float dppmax(float m) {
    int t = __builtin_amdgcn_update_dpp(0xFF800000, __float_as_int(m),
                                        CTRL, RM, 0xf, false);
    return fmaxf(m, __int_as_float(t));
}

__global__ __launch_bounds__(64) void topk_dense(const float* __restrict__ D,
                                                 const float* __restrict__ GN,
                                                 const float* __restrict__ W,
                                                 _Float16* __restrict__ Bt) {
    const int u = blockIdx.x;
    const int l = threadIdx.x;

    float cand[16];
#pragma unroll
    for (int j = 0; j < 16; ++j) {
        int i = l + 64 * j;                          // coalesced
        cand[j] = D[u * IN_DIM + i] + GN[u * IN_DIM + i];
    }

    int mykeep = -1;

    for (int t = 0; t < KCONN; ++t) {
        float bv = cand[0];
        int bs = 0;
#pragma unroll
        for (int j = 1; j < 16; ++j) {
            bool gt = cand[j] > bv;
            bv = gt ? cand[j] : bv;
            bs = gt ? j : bs;
        }
        float m = bv;
        m = dppmax<0x111, 0xf>(m);
        m = dppmax<0x112, 0xf>(m);
        m = dppmax<0x114, 0xf>(m);
        m = dppmax<0x118, 0xf>(m);
        m = dppmax<0x142, 0xa>(m);   // row_bcast15 -> rows 1,3
        m = dppmax<0x143, 0xc>(m);   // row_bcast31 -> rows 2,3
        float gmax = __int_as_float(__builtin_amdgcn_readlane(__float_as_int(m), 63));

        unsigned long long mask = __ballot(bv == gmax);
        int owner = __ffsll((long long)mask) - 1;
        int slot = __builtin_amdgcn_readlane(bs, owner);
        int idx = slot * 64 + owner;

        if (l == t) mykeep = idx;
        bool own = (l == owner);
#pragma unroll
        for (int j = 0; j < 16; ++j)
            cand[j] = (own && j == slot) ? -__builtin_huge_valf() : cand[j];
    }

    __shared__ uint32_t rowbuf[IN_DIM / 2];          // 1024 f16 = 2 KB
#pragma unroll
    for (int j = 0; j < 8; ++j) rowbuf[l + 64 * j] = 0;
    __syncthreads();
    if (l < KCONN) {
        union { _Float16 h; uint16_t b; } cv;
        cv.h = (_Float16)W[u * IN_DIM + mykeep];
        ((uint16_t*)rowbuf)[mykeep] = cv.b;
    }
    __syncthreads();
    uint4* out = (uint4*)(Bt + (size_t)u * IN_DIM);
    const uint4* rb = (const uint4*)rowbuf;
    out[l]      = rb[l];
    out[l + 64] = rb[l + 64];
}

// ---------------- Kernel 2: dense f16 MFMA GEMM, 2-phase pipeline ----------------
// y[16384][512] = x(f32->f16)[M][K] @ Bt[N][K]^T + bias
// BM=64, BN=128, BK=64, 4 waves, grid 1024 -> 4 blocks/CU. LDS 48 KB dbuf.
// Per iter (ONE __syncthreads):
//   gloadB(ks+1)->Bs[nxt]   (L2 ~250cyc, hides under compute)
//   compute(cur)            (12 ds_read_b128 + 16 MFMA)
//   cvtwrite v->As[nxt]     (v arrived during compute)
//   __syncthreads()         (drains B gloads + ds writes)
//   v = load x(ks+2)        (issued post-barrier -> never drained; ~900cyc
//                            HBM latency hides under next compute+barrier)
// Swizzles identical to r10 (verified: 0 conflicts): phys = row*128 +
// (kbyte ^ ((row&7)<<4)); B global source pre-swizzled, LDS linear (rule #21).
// XCD map: swz=(bid&7)*128+(bid>>3) -> XCD pair owns one n-tile (B L2-hot),
// x re-reads across n-tiles land in L3.

typedef const uint32_t __attribute__((address_space(1)))* gp1_t;
typedef uint32_t __attribute__((address_space(3)))* lp3_t;

__device__ __forceinline__ void gload16(const void* g, void* l) {
    __builtin_amdgcn_global_load_lds((gp1_t)g, (lp3_t)l, 16, 0, 0);
}

__device__ __forceinline__ uint32_t pkrtz(float a, float b) {
    union { hf16x2 h; uint32_t u; } cv;
    cv.h = __builtin_amdgcn_cvt_pkrtz(a, b);
    return cv.u;
}

__global__ __launch_bounds__(NT, 4) void gemm_kernel(const float* __restrict__ x,
                                                     const float* __restrict__ bias,
                                                     const _Float16* __restrict__ Bt,
                                                     float* __restrict__ y) {
    __shared__ char As[2][BM * 128];                // 2 x 8 KB
    __shared__ char Bs[2][BN * 128];                // 2 x 16 KB

    const int tid = threadIdx.x;
    const int w = tid >> 6;                         // wave 0..3
    const int l = tid & 63;
    const int swz = ((int)blockIdx.x & 7) * 128 + ((int)blockIdx.x >> 3);
    const int mb = (swz & 255) * BM;
    const int nb = (swz >> 8) * BN;

    // A staging: thread t -> row t>>2, k-quarter t&3 (16 f32 = 4 float4)
    const int arow = tid >> 2;
    const int akq = tid & 3;
    const float* xp0 = x + (size_t)(mb + arow) * IN_DIM + akq * 16;
    char* asw = (char*)0;  // per-buffer below
    const uint32_t akb0 = (uint32_t)(akq * 32) ^ (uint32_t)((arow & 7) << 4);
    const uint32_t akb1 = akb0 ^ 16u;

    // B staging: call c of wave w -> seg = w*4+c (8 rows); lane: row seg*8+(l>>3),
    // chunk (l&7). Global source pre-swizzled (involution with read XOR).
    const int brow = l >> 3;
    const char* btb = (const char*)Bt + (size_t)(nb + brow) * (IN_DIM * 2) +
                      (uint32_t)(((l & 7) ^ brow) << 4);

    float4 v0, v1, v2, v3;
    f32x4 acc[4][2] = {};

#define LOADV(kss)                                                               \
    {                                                                            \
        const float4* p = (const float4*)(xp0 + (size_t)(kss) * BK);             \
        v0 = p[0]; v1 = p[1]; v2 = p[2]; v3 = p[3];                              \
    }

#define CVTWRITE(buf)                                                            \
    {                                                                            \
        asw = As[buf] + arow * 128;                                              \
        *(uint4*)(asw + akb0) = make_uint4(pkrtz(v0.x, v0.y), pkrtz(v0.z, v0.w), \
                                           pkrtz(v1.x, v1.y), pkrtz(v1.z, v1.w));\
        *(uint4*)(asw + akb1) = make_uint4(pkrtz(v2.x, v2.y), pkrtz(v2.z, v2.w), \
                                           pkrtz(v3.x, v3.y), pkrtz(v3.z, v3.w));\
    }

#define GLOADB(buf, kss)                                                         \
    {                                                                            \
        const size_t kso = (size_t)(kss) * 128;                                  \
        _Pragma("unroll")                                                        \
        for (int c = 0; c < 4; ++c) {                                            \
            const int seg = w * 4 + c;                                           \
            gload16(btb + (size_t)seg * 8 * (IN_DIM * 2) + kso,                  \
                    Bs[buf] + seg * 1024);                                       \
        }                                                                        \
    }

#define COMPUTE(buf)                                                             \
    {                                                                            \
        _Pragma("unroll")                                                        \
        for (int kh = 0; kh < 2; ++kh) {                                         \
            const uint32_t kb = (uint32_t)(kh * 64 + ((l >> 4) << 4));           \
            f16x8 af[4], bf[2];                                                  \
            _Pragma("unroll")                                                    \
            for (int mf = 0; mf < 4; ++mf) {                                     \
                const int row = mf * 16 + (l & 15);                              \
                af[mf] = *(const f16x8*)(As[buf] + row * 128 +                   \
                                         (kb ^ ((row & 7) << 4)));               \
            }                                                                    \
            _Pragma("unroll")                                                    \
            for (int nf = 0; nf < 2; ++nf) {                                     \
                const int row = w * 32 + nf * 16 + (l & 15);                     \
                bf[nf] = *(const f16x8*)(Bs[buf] + row * 128 +                   \
                                         (kb ^ ((row & 7) << 4)));               \
            }                                                                    \
            _Pragma("unroll")                                                    \
            for (int mf = 0; mf < 4; ++mf)                                       \
                _Pragma("unroll")                                                \
                for (int nf = 0; nf < 2; ++nf)                                   \
                    acc[mf][nf] = __builtin_amdgcn_mfma_f32_16x16x32_f16(        \
                        af[mf], bf[nf], acc[mf][nf], 0, 0, 0);                   \
        }                                                                        \
    }

    // ---- prologue ----
    LOADV(0);
    CVTWRITE(0);
    GLOADB(0, 0);
    __syncthreads();
    LOADV(1);

    // ---- main loop: one barrier per K-step ----
    for (int ks = 0; ks < KS - 1; ++ks) {
        const int cur = ks & 1, nxt = cur ^ 1;
        GLOADB(nxt, ks + 1);
        COMPUTE(cur);
        CVTWRITE(nxt);
        __syncthreads();
        LOADV(ks + 2 < KS ? ks + 2 : KS - 1);       // tail reload, unused
    }
    COMPUTE((KS - 1) & 1);

    // ---- epilogue: y = acc + bias ----
#pragma unroll
    for (int nf = 0; nf < 2; ++nf) {
        const int n = nb + w * 32 + nf * 16 + (l & 15);
        const float bv = bias[n];
#pragma unroll
        for (int mf = 0; mf < 4; ++mf) {
            const int m0 = mb + mf * 16 + ((l >> 4) << 2);
#pragma unroll
            for (int r = 0; r < 4; ++r)
                y[(size_t)(m0 + r) * UNITS + n] = acc[mf][nf][r] + bv;
        }
    }
#undef LOADV
#undef CVTWRITE
#undef GLOADB
#undef COMPUTE
}

extern "C" void kernel_launch(void* const* d_in, const int* in_sizes, int n_in,
                              void* d_out, int out_size, void* d_ws, size_t ws_size,
                              hipStream_t stream) {
    const float* x  = (const float*)d_in[0];   // [16384,1024]
    const float* W  = (const float*)d_in[1];   // [512,1024]
    const float* bv = (const float*)d_in[2];   // [512]
    const float* D  = (const float*)d_in[3];   // [512,1024]
    const float* GN = (const float*)d_in[4];   // [1,512,1024]
    float* y = (float*)d_out;                  // [16384,512]

    _Float16* Bt = (_Float16*)d_ws;            // 512*1024*2B = 1 MB scratch

    topk_dense<<<UNITS, 64, 0, stream>>>(D, GN, W, Bt);
    gemm_kernel<<<(BATCH / BM) * (UNITS / BN), NT, 0, stream>>>(x, bv, Bt, y);
}

// Round 12
// 61.674 us; speedup vs baseline: 1.3243x; 1.3243x over previous
//
#include <hip/hip_runtime.h>
#include <stdint.h>

#define UNITS  512
#define IN_DIM 1024
#define KCONN  32
#define BATCH  16384

#define BM 64
#define BK 32
#define NT 512            // 8 waves
#define KS (IN_DIM / BK)  // 32 K-steps

typedef _Float16 f16x8 __attribute__((ext_vector_type(8)));
typedef __fp16   hf16x2 __attribute__((ext_vector_type(2)));
typedef float    f32x4 __attribute__((ext_vector_type(4)));

// ---------------- Kernel 1: top-32 per unit -> packed B tiles ----------------
// DPP top-32 selection (r5-r8 verified). Output wsB: per K-step ks (32 f16 k),
// a contiguous 32 KB block [row=512][64 B], chunk-swizzled for the GEMM's LDS:
//   wsB[ks*32768 + u*64 + ((c ^ ((u>>1)&3))<<4)] = natural 16B chunk c of
//   (f16)W'[u, ks*32 + c*8 .. +8]   (W' = W masked to the top-32 index set).
// GEMM stages these blocks with LINEAR global_load_lds (rule #21) and reads
// fragments with the same XOR -> involution, 2-way banks max (free, m136).

template <int CTRL, int RM>
__device__ __forceinline__ float dppmax(float m) {
    int t = __builtin_amdgcn_update_dpp(0xFF800000, __float_as_int(m),
                                        CTRL, RM, 0xf, false);
    return fmaxf(m, __int_as_float(t));
}

__global__ __launch_bounds__(64) void topk_pack(const float* __restrict__ D,
                                                const float* __restrict__ GN,
                                                const float* __restrict__ W,
                                                char* __restrict__ wsB) {
    const int u = blockIdx.x;
    const int l = threadIdx.x;

    float cand[16];
#pragma unroll
    for (int j = 0; j < 16; ++j) {
        int i = l + 64 * j;                          // coalesced
        cand[j] = D[u * IN_DIM + i] + GN[u * IN_DIM + i];
    }

    int mykeep = -1;

    for (int t = 0; t < KCONN; ++t) {
        float bv = cand[0];
        int bs = 0;
#pragma unroll
        for (int j = 1; j < 16; ++j) {
            bool gt = cand[j] > bv;
            bv = gt ? cand[j] : bv;
            bs = gt ? j : bs;
        }
        float m = bv;
        m = dppmax<0x111, 0xf>(m);
        m = dppmax<0x112, 0xf>(m);
        m = dppmax<0x114, 0xf>(m);
        m = dppmax<0x118, 0xf>(m);
        m = dppmax<0x142, 0xa>(m);   // row_bcast15 -> rows 1,3
        m = dppmax<0x143, 0xc>(m);   // row_bcast31 -> rows 2,3
        float gmax = __int_as_float(__builtin_amdgcn_readlane(__float_as_int(m), 63));

        unsigned long long mask = __ballot(bv == gmax);
        int owner = __ffsll((long long)mask) - 1;
        int slot = __builtin_amdgcn_readlane(bs, owner);
        int idx = slot * 64 + owner;

        if (l == t) mykeep = idx;
        bool own = (l == owner);
#pragma unroll
        for (int j = 0; j < 16; ++j)
            cand[j] = (own && j == slot) ? -__builtin_huge_valf() : cand[j];
    }

    __shared__ uint32_t rowbuf[IN_DIM / 2];          // dense f16 row, 2 KB
#pragma unroll
    for (int j = 0; j < 8; ++j) rowbuf[l + 64 * j] = 0;
    __syncthreads();
    if (l < KCONN) {
        union { _Float16 h; uint16_t b; } cv;
        cv.h = (_Float16)W[u * IN_DIM + mykeep];
        ((uint16_t*)rowbuf)[mykeep] = cv.b;
    }
    __syncthreads();

    const int sw = (u >> 1) & 3;
#pragma unroll
    for (int j = 0; j < 2; ++j) {
        const int g = l + 64 * j;                    // 16B chunk id 0..127
        const int ks = g >> 2, c = g & 3;
        uint4 d = ((const uint4*)rowbuf)[g];
        *(uint4*)(wsB + (size_t)ks * 32768 + u * 64 + ((c ^ sw) << 4)) = d;
    }
}

// ---------------- Kernel 2: full-N f16 MFMA GEMM ----------------
// y[16384][512] = x(f32->f16) @ W'^T + bias.  One block = 64 m x FULL N=512.
// grid 256 -> x read from HBM exactly ONCE (the r11 FETCH-doubling fix).
// B (1 MB) is L2-resident on every XCD. LDS 72 KB dbuf; one barrier/K-step:
//   GLOADB(nxt)   4x linear global_load_lds (L2 ~300cyc, hides under compute)
//   COMPUTE(cur)  8x ds_read_b128 + 16x MFMA 16x16x32_f16 (layouts r10-verified)
//   CVTWRITE(nxt) x(f32)->pkrtz->8B ds_write (x arrived during prev iter)
//   __syncthreads(); LOADV(ks+2)  (x float4 issued post-barrier, never drained)

typedef const uint32_t __attribute__((address_space(1)))* gp1_t;
typedef uint32_t __attribute__((address_space(3)))* lp3_t;

__device__ __forceinline__ void gload16(const void* g, void* l) {
    __builtin_amdgcn_global_load_lds((gp1_t)g, (lp3_t)l, 16, 0, 0);
}

__device__ __forceinline__ uint32_t pkrtz(float a, float b) {
    union { hf16x2 h; uint32_t u; } cv;
    cv.h = __builtin_amdgcn_cvt_pkrtz(a, b);
    return cv.u;
}

__global__ __launch_bounds__(NT, 2) void gemm_kernel(const float* __restrict__ x,
                                                     const float* __restrict__ bias,
                                                     const char* __restrict__ wsB,
                                                     float* __restrict__ y) {
    __shared__ char As[2][BM * 64];                 // 2 x 4 KB (64 rows x 32 f16)
    __shared__ char Bs[2][UNITS * 64];              // 2 x 32 KB (512 rows x 32 f16)

    const int tid = threadIdx.x;
    const int w = tid >> 6;                         // wave 0..7
    const int l = tid & 63;
    const int mb = (int)blockIdx.x * BM;

    // A staging: thread -> row tid>>3, f32-quad kq = tid&7 (4 f32 -> 8B f16)
    const int arow = tid >> 3;
    const int akq = tid & 7;
    const float* xp0 = x + (size_t)(mb + arow) * IN_DIM + akq * 4;
    const uint32_t aoff = (uint32_t)(arow * 64) +
                          ((uint32_t)((akq >> 1) ^ ((arow >> 1) & 3)) << 4) +
                          (uint32_t)((akq & 1) << 3);

    float4 v;
    f32x4 acc[4][4] = {};

#define LOADV(kss) v = *(const float4*)(xp0 + (size_t)(kss) * BK);

#define CVTWRITE(buf)                                                            \
    *(uint2*)(As[buf] + aoff) = make_uint2(pkrtz(v.x, v.y), pkrtz(v.z, v.w));

#define GLOADB(buf, kss)                                                         \
    {                                                                            \
        const char* src = wsB + (size_t)(kss) * 32768 + tid * 16;                \
        _Pragma("unroll")                                                        \
        for (int rr = 0; rr < 4; ++rr)                                           \
            gload16(src + rr * 8192, Bs[buf] + rr * 8192 + tid * 16);            \
    }

#define COMPUTE(buf)                                                             \
    {                                                                            \
        const uint32_t kc = (uint32_t)(l >> 4);                                  \
        f16x8 af[4], bf[4];                                                      \
        _Pragma("unroll")                                                        \
        for (int mf = 0; mf < 4; ++mf) {                                         \
            const int row = mf * 16 + (l & 15);                                  \
            af[mf] = *(const f16x8*)(As[buf] + row * 64 +                        \
                                     ((kc ^ ((row >> 1) & 3)) << 4));            \
        }                                                                        \
        _Pragma("unroll")                                                        \
        for (int nf = 0; nf < 4; ++nf) {                                         \
            const int row = w * 64 + nf * 16 + (l & 15);                         \
            bf[nf] = *(const f16x8*)(Bs[buf] + row * 64 +                        \
                                     ((kc ^ ((row >> 1) & 3)) << 4));            \
        }                                                                        \
        _Pragma("unroll")                                                        \
        for (int mf = 0; mf < 4; ++mf)                                           \
            _Pragma("unroll")                                                    \
            for (int nf = 0; nf < 4; ++nf)                                       \
                acc[mf][nf] = __builtin_amdgcn_mfma_f32_16x16x32_f16(            \
                    af[mf], bf[nf], acc[mf][nf], 0, 0, 0);                       \
    }

    // ---- prologue ----
    LOADV(0);
    GLOADB(0, 0);
    CVTWRITE(0);
    __syncthreads();
    LOADV(1);

    // ---- main loop: one barrier per K-step ----
    for (int ks = 0; ks < KS - 1; ++ks) {
        const int cur = ks & 1, nxt = cur ^ 1;
        GLOADB(nxt, ks + 1);
        COMPUTE(cur);
        CVTWRITE(nxt);
        __syncthreads();
        LOADV(ks + 2 < KS ? ks + 2 : KS - 1);       // tail reload, unused
    }
    COMPUTE((KS - 1) & 1);

    // ---- epilogue: y = acc + bias ----
#pragma unroll
    for (int nf = 0; nf < 4; ++nf) {
        const int n = w * 64 + nf * 16 + (l & 15);
        const float bv = bias[n];
#pragma unroll
        for (int mf = 0; mf < 4; ++mf) {
            const int m0 = mb + mf * 16 + ((l >> 4) << 2);
#pragma unroll
            for (int r = 0; r < 4; ++r)
                y[(size_t)(m0 + r) * UNITS + n] = acc[mf][nf][r] + bv;
        }
    }
#undef LOADV
#undef CVTWRITE
#undef GLOADB
#undef COMPUTE
}

extern "C" void kernel_launch(void* const* d_in, const int* in_sizes, int n_in,
                              void* d_out, int out_size, void* d_ws, size_t ws_size,
                              hipStream_t stream) {
    const float* x  = (const float*)d_in[0];   // [16384,1024]
    const float* W  = (const float*)d_in[1];   // [512,1024]
    const float* bv = (const float*)d_in[2];   // [512]
    const float* D  = (const float*)d_in[3];   // [512,1024]
    const float* GN = (const float*)d_in[4];   // [1,512,1024]
    float* y = (float*)d_out;                  // [16384,512]

    char* wsB = (char*)d_ws;                   // 32 steps x 32 KB = 1 MB

    topk_pack<<<UNITS, 64, 0, stream>>>(D, GN, W, wsB);
    gemm_kernel<<<BATCH / BM, NT, 0, stream>>>(x, bv, wsB, y);
}

// Round 13
// 60.837 us; speedup vs baseline: 1.3425x; 1.0138x over previous
//
#include <hip/hip_runtime.h>
#include <stdint.h>

#define UNITS  512
#define IN_DIM 1024
#define KCONN  32
#define BATCH  16384

#define BM 64
#define BN 256
#define BK 32
#define NT 512            // 8 waves
#define KS (IN_DIM / BK)  // 32 K-steps

typedef _Float16 f16x8 __attribute__((ext_vector_type(8)));
typedef __fp16   hf16x2 __attribute__((ext_vector_type(2)));
typedef float    f32x4 __attribute__((ext_vector_type(4)));

// ---------------- Kernel 1: top-32 per unit -> packed B tiles ----------------
// DPP top-32 selection (r5-r12 verified). Output wsB: per K-step ks, a
// contiguous 32 KB block [u=512][64 B], chunk-swizzled for the GEMM's LDS:
//   wsB[ks*32768 + u*64 + ((c ^ ((u>>1)&3))<<4)] = natural 16B chunk c of
//   (f16)W'[u, ks*32 + c*8 .. +8]   (W' = W masked to the top-32 index set).
// GEMM stages with LINEAR global_load_lds (rule #21), reads with the same XOR.

template <int CTRL, int RM>
__device__ __forceinline__ float dppmax(float m) {
    int t = __builtin_amdgcn_update_dpp(0xFF800000, __float_as_int(m),
                                        CTRL, RM, 0xf, false);
    return fmaxf(m, __int_as_float(t));
}

__global__ __launch_bounds__(64) void topk_pack(const float* __restrict__ D,
                                                const float* __restrict__ GN,
                                                const float* __restrict__ W,
                                                char* __restrict__ wsB) {
    const int u = blockIdx.x;
    const int l = threadIdx.x;

    float cand[16];
#pragma unroll
    for (int j = 0; j < 16; ++j) {
        int i = l + 64 * j;                          // coalesced
        cand[j] = D[u * IN_DIM + i] + GN[u * IN_DIM + i];
    }

    int mykeep = -1;

    for (int t = 0; t < KCONN; ++t) {
        float bv = cand[0];
        int bs = 0;
#pragma unroll
        for (int j = 1; j < 16; ++j) {
            bool gt = cand[j] > bv;
            bv = gt ? cand[j] : bv;
            bs = gt ? j : bs;
        }
        float m = bv;
        m = dppmax<0x111, 0xf>(m);
        m = dppmax<0x112, 0xf>(m);
        m = dppmax<0x114, 0xf>(m);
        m = dppmax<0x118, 0xf>(m);
        m = dppmax<0x142, 0xa>(m);   // row_bcast15 -> rows 1,3
        m = dppmax<0x143, 0xc>(m);   // row_bcast31 -> rows 2,3
        float gmax = __int_as_float(__builtin_amdgcn_readlane(__float_as_int(m), 63));

        unsigned long long mask = __ballot(bv == gmax);
        int owner = __ffsll((long long)mask) - 1;
        int slot = __builtin_amdgcn_readlane(bs, owner);
        int idx = slot * 64 + owner;

        if (l == t) mykeep = idx;
        bool own = (l == owner);
#pragma unroll
        for (int j = 0; j < 16; ++j)
            cand[j] = (own && j == slot) ? -__builtin_huge_valf() : cand[j];
    }

    __shared__ uint32_t rowbuf[IN_DIM / 2];          // dense f16 row, 2 KB
#pragma unroll
    for (int j = 0; j < 8; ++j) rowbuf[l + 64 * j] = 0;
    __syncthreads();
    if (l < KCONN) {
        union { _Float16 h; uint16_t b; } cv;
        cv.h = (_Float16)W[u * IN_DIM + mykeep];
        ((uint16_t*)rowbuf)[mykeep] = cv.b;
    }
    __syncthreads();

    const int sw = (u >> 1) & 3;
#pragma unroll
    for (int j = 0; j < 2; ++j) {
        const int g = l + 64 * j;                    // 16B chunk id 0..127
        const int ks = g >> 2, c = g & 3;
        uint4 d = ((const uint4*)rowbuf)[g];
        *(uint4*)(wsB + (size_t)ks * 32768 + u * 64 + ((c ^ sw) << 4)) = d;
    }
}

// ---------------- Kernel 2: f16 MFMA GEMM, BN=256, 2-4 blocks/CU ----------------
// y[16384][512] = x(f32->f16) @ W'^T + bias.  Block = 64 m x 256 n, grid 512
// (bid>>1 = m-tile, bid&1 = n-half: pairs share x via L3).  LDS 40 KB dbuf ->
// up to 4 blocks/CU (the r12 fix: 1 block/CU had zero overlap work, ~75% of
// each K-step was exposed latency at the lockstep barrier).
// Per iter (one __syncthreads):
//   GLOADB(nxt)  2x linear global_load_lds (16 KB; L2-resident B)
//   COMPUTE(cur) 6x ds_read_b128 + 8x MFMA 16x16x32_f16 (r10-verified layouts)
//   CVTWRITE(nxt); barrier; LOADV(ks+2) (post-barrier, never drained)

typedef const uint32_t __attribute__((address_space(1)))* gp1_t;
typedef uint32_t __attribute__((address_space(3)))* lp3_t;

__device__ __forceinline__ void gload16(const void* g, void* l) {
    __builtin_amdgcn_global_load_lds((gp1_t)g, (lp3_t)l, 16, 0, 0);
}

__device__ __forceinline__ uint32_t pkrtz(float a, float b) {
    union { hf16x2 h; uint32_t u; } cv;
    cv.h = __builtin_amdgcn_cvt_pkrtz(a, b);
    return cv.u;
}

__global__ __launch_bounds__(NT, 4) void gemm_kernel(const float* __restrict__ x,
                                                     const float* __restrict__ bias,
                                                     const char* __restrict__ wsB,
                                                     float* __restrict__ y) {
    __shared__ char As[2][BM * 64];                 // 2 x 4 KB (64 rows x 32 f16)
    __shared__ char Bs[2][BN * 64];                 // 2 x 16 KB (256 rows x 32 f16)

    const int tid = threadIdx.x;
    const int w = tid >> 6;                         // wave 0..7
    const int l = tid & 63;
    const int mb = ((int)blockIdx.x >> 1) * BM;
    const int nb = ((int)blockIdx.x & 1) * BN;

    // A staging: thread -> row tid>>3, f32-quad kq = tid&7 (4 f32 -> 8B f16)
    const int arow = tid >> 3;
    const int akq = tid & 7;
    const float* xp0 = x + (size_t)(mb + arow) * IN_DIM + akq * 4;
    const uint32_t aoff = (uint32_t)(arow * 64) +
                          ((uint32_t)((akq >> 1) ^ ((arow >> 1) & 3)) << 4) +
                          (uint32_t)((akq & 1) << 3);

    float4 v;
    f32x4 acc[4][2] = {};

#define LOADV(kss) v = *(const float4*)(xp0 + (size_t)(kss) * BK);

#define CVTWRITE(buf)                                                            \
    *(uint2*)(As[buf] + aoff) = make_uint2(pkrtz(v.x, v.y), pkrtz(v.z, v.w));

#define GLOADB(buf, kss)                                                         \
    {                                                                            \
        const char* src = wsB + (size_t)(kss) * 32768 + (size_t)nb * 64 +        \
                          tid * 16;                                              \
        _Pragma("unroll")                                                        \
        for (int rr = 0; rr < 2; ++rr)                                           \
            gload16(src + rr * 8192, Bs[buf] + rr * 8192 + tid * 16);            \
    }

#define COMPUTE(buf)                                                             \
    {                                                                            \
        const uint32_t kc = (uint32_t)(l >> 4);                                  \
        f16x8 af[4], bf[2];                                                      \
        _Pragma("unroll")                                                        \
        for (int mf = 0; mf < 4; ++mf) {                                         \
            const int row = mf * 16 + (l & 15);                                  \
            af[mf] = *(const f16x8*)(As[buf] + row * 64 +                        \
                                     ((kc ^ ((row >> 1) & 3)) << 4));            \
        }                                                                        \
        _Pragma("unroll")                                                        \
        for (int nf = 0; nf < 2; ++nf) {                                         \
            const int row = w * 32 + nf * 16 + (l & 15);                         \
            bf[nf] = *(const f16x8*)(Bs[buf] + row * 64 +                        \
                                     ((kc ^ ((row >> 1) & 3)) << 4));            \
        }                                                                        \
        _Pragma("unroll")                                                        \
        for (int mf = 0; mf < 4; ++mf)                                           \
            _Pragma("unroll")                                                    \
            for (int nf = 0; nf < 2; ++nf)                                       \
                acc[mf][nf] = __builtin_amdgcn_mfma_f32_16x16x32_f16(            \
                    af[mf], bf[nf], acc[mf][nf], 0, 0, 0);                       \
    }

    // ---- prologue ----
    LOADV(0);
    GLOADB(0, 0);
    CVTWRITE(0);
    __syncthreads();
    LOADV(1);

    // ---- main loop: one barrier per K-step ----
    for (int ks = 0; ks < KS - 1; ++ks) {
        const int cur = ks & 1, nxt = cur ^ 1;
        GLOADB(nxt, ks + 1);
        COMPUTE(cur);
        CVTWRITE(nxt);
        __syncthreads();
        LOADV(ks + 2 < KS ? ks + 2 : KS - 1);       // tail reload, unused
    }
    COMPUTE((KS - 1) & 1);

    // ---- epilogue: y = acc + bias ----
#pragma unroll
    for (int nf = 0; nf < 2; ++nf) {
        const int n = nb + w * 32 + nf * 16 + (l & 15);
        const float bv = bias[n];
#pragma unroll
        for (int mf = 0; mf < 4; ++mf) {
            const int m0 = mb + mf * 16 + ((l >> 4) << 2);
#pragma unroll
            for (int r = 0; r < 4; ++r)
                y[(size_t)(m0 + r) * UNITS + n] = acc[mf][nf][r] + bv;
        }
    }
#undef LOADV
#undef CVTWRITE
#undef GLOADB
#undef COMPUTE
}

extern "C" void kernel_launch(void* const* d_in, const int* in_sizes, int n_in,
                              void* d_out, int out_size, void* d_ws, size_t ws_size,
                              hipStream_t stream) {
    const float* x  = (const float*)d_in[0];   // [16384,1024]
    const float* W  = (const float*)d_in[1];   // [512,1024]
    const float* bv = (const float*)d_in[2];   // [512]
    const float* D  = (const float*)d_in[3];   // [512,1024]
    const float* GN = (const float*)d_in[4];   // [1,512,1024]
    float* y = (float*)d_out;                  // [16384,512]

    char* wsB = (char*)d_ws;                   // 32 steps x 32 KB = 1 MB

    topk_pack<<<UNITS, 64, 0, stream>>>(D, GN, W, wsB);
    gemm_kernel<<<(BATCH / BM) * (UNITS / BN), NT, 0, stream>>>(x, bv, wsB, y);
}

// Round 14
// 49.862 us; speedup vs baseline: 1.6380x; 1.2201x over previous
//
#include <hip/hip_runtime.h>
#include <stdint.h>

#define UNITS  512
#define IN_DIM 1024
#define KCONN  32
#define BATCH  16384

#define BM 64
#define BN 256
#define BK 64
#define NT 512            // 8 waves
#define KS (IN_DIM / BK)  // 16 K-steps

typedef _Float16 f16x8 __attribute__((ext_vector_type(8)));
typedef __fp16   hf16x2 __attribute__((ext_vector_type(2)));
typedef float    f32x4 __attribute__((ext_vector_type(4)));

// ---------------- Kernel 1: top-32 per unit -> packed B tiles ----------------
// DPP top-32 selection (r5-r13 verified). wsB: per 32-k block kb (32 KB each):
//   wsB[kb*32768 + u*64 + ((c ^ ((u>>1)&3))<<4)] = 16B chunk c of (f16)W'[u,...]
// GEMM stages two consecutive blocks per BK=64 step with LINEAR global_load_lds
// (rule #21) and reads fragments with the same XOR (r12/r13: 0 conflicts).

template <int CTRL, int RM>
__device__ __forceinline__ float dppmax(float m) {
    int t = __builtin_amdgcn_update_dpp(0xFF800000, __float_as_int(m),
                                        CTRL, RM, 0xf, false);
    return fmaxf(m, __int_as_float(t));
}

__global__ __launch_bounds__(64) void topk_pack(const float* __restrict__ D,
                                                const float* __restrict__ GN,
                                                const float* __restrict__ W,
                                                char* __restrict__ wsB) {
    const int u = blockIdx.x;
    const int l = threadIdx.x;

    float cand[16];
#pragma unroll
    for (int j = 0; j < 16; ++j) {
        int i = l + 64 * j;                          // coalesced
        cand[j] = D[u * IN_DIM + i] + GN[u * IN_DIM + i];
    }

    int mykeep = -1;

    for (int t = 0; t < KCONN; ++t) {
        float bv = cand[0];
        int bs = 0;
#pragma unroll
        for (int j = 1; j < 16; ++j) {
            bool gt = cand[j] > bv;
            bv = gt ? cand[j] : bv;
            bs = gt ? j : bs;
        }
        float m = bv;
        m = dppmax<0x111, 0xf>(m);
        m = dppmax<0x112, 0xf>(m);
        m = dppmax<0x114, 0xf>(m);
        m = dppmax<0x118, 0xf>(m);
        m = dppmax<0x142, 0xa>(m);   // row_bcast15 -> rows 1,3
        m = dppmax<0x143, 0xc>(m);   // row_bcast31 -> rows 2,3
        float gmax = __int_as_float(__builtin_amdgcn_readlane(__float_as_int(m), 63));

        unsigned long long mask = __ballot(bv == gmax);
        int owner = __ffsll((long long)mask) - 1;
        int slot = __builtin_amdgcn_readlane(bs, owner);
        int idx = slot * 64 + owner;

        if (l == t) mykeep = idx;
        bool own = (l == owner);
#pragma unroll
        for (int j = 0; j < 16; ++j)
            cand[j] = (own && j == slot) ? -__builtin_huge_valf() : cand[j];
    }

    __shared__ uint32_t rowbuf[IN_DIM / 2];          // dense f16 row, 2 KB
#pragma unroll
    for (int j = 0; j < 8; ++j) rowbuf[l + 64 * j] = 0;
    __syncthreads();
    if (l < KCONN) {
        union { _Float16 h; uint16_t b; } cv;
        cv.h = (_Float16)W[u * IN_DIM + mykeep];
        ((uint16_t*)rowbuf)[mykeep] = cv.b;
    }
    __syncthreads();

    const int sw = (u >> 1) & 3;
#pragma unroll
    for (int j = 0; j < 2; ++j) {
        const int g = l + 64 * j;                    // 16B chunk id 0..127
        const int kb = g >> 2, c = g & 3;
        uint4 d = ((const uint4*)rowbuf)[g];
        *(uint4*)(wsB + (size_t)kb * 32768 + u * 64 + ((c ^ sw) << 4)) = d;
    }
}

// ---------------- Kernel 2: f16 MFMA GEMM, counted-vmcnt pipeline ----------------
// y = x(f32->f16) @ W'^T + bias.  BM=64 x BN=256, BK=64, 8 waves, grid 512,
// LDS 80 KB -> 2 blocks/CU.  The r13 fix: __syncthreads' vmcnt(0) drain
// re-exposed x's ~900cyc HBM latency at every barrier. Now (T4):
//   iter ks: GLOADB(nxt,ks+1) [oldest, 4 ops] ; fence ; COMPUTE(cur)
//            CVTWRITE(nxt, v(ks+1)) [compiler auto-waits the v regs]
//            LOADV(v(ks+3)) [newest, 2 ops] ; swap va/vb
//            s_waitcnt vmcnt(2) lgkmcnt(0)   <- B landed, x prefetches FLY ON
//            s_barrier
// x is consumed ~2 barrier-intervals after issue -> HBM latency covered.

typedef const uint32_t __attribute__((address_space(1)))* gp1_t;
typedef uint32_t __attribute__((address_space(3)))* lp3_t;

__device__ __forceinline__ void gload16(const void* g, void* l) {
    __builtin_amdgcn_global_load_lds((gp1_t)g, (lp3_t)l, 16, 0, 0);
}

__device__ __forceinline__ uint32_t pkrtz(float a, float b) {
    union { hf16x2 h; uint32_t u; } cv;
    cv.h = __builtin_amdgcn_cvt_pkrtz(a, b);
    return cv.u;
}

#define FENCE() asm volatile("" ::: "memory")

__global__ __launch_bounds__(NT, 4) void gemm_kernel(const float* __restrict__ x,
                                                     const float* __restrict__ bias,
                                                     const char* __restrict__ wsB,
                                                     float* __restrict__ y) {
    __shared__ char As[2][BM * 128];                // 2 x 8 KB (two 4K 32-k halves)
    __shared__ char Bs[2][BN * 128];                // 2 x 32 KB (two 16K 32-k halves)

    const int tid = threadIdx.x;
    const int w = tid >> 6;                         // wave 0..7
    const int l = tid & 63;
    const int mb = ((int)blockIdx.x >> 1) * BM;
    const int nb = ((int)blockIdx.x & 1) * BN;

    // A staging: thread -> row tid>>3, k-octet akq = tid&7 (8 f32 -> 16B f16)
    const int arow = tid >> 3;
    const int akq = tid & 7;
    const float* xp0 = x + (size_t)(mb + arow) * IN_DIM + akq * 8;
    const uint32_t aoff = (uint32_t)((akq >> 2) * 4096) + (uint32_t)(arow * 64) +
                          ((uint32_t)((akq & 3) ^ ((arow >> 1) & 3)) << 4);

    float4 va1, va2, vb1, vb2;
    f32x4 acc[4][2] = {};

#define LOADV(r1, r2, kss)                                                       \
    {                                                                            \
        const float4* p = (const float4*)(xp0 + (size_t)(kss) * BK);             \
        r1 = p[0]; r2 = p[1];                                                    \
    }

#define CVTWRITE(buf, r1, r2)                                                    \
    *(uint4*)(As[buf] + aoff) = make_uint4(pkrtz(r1.x, r1.y), pkrtz(r1.z, r1.w), \
                                           pkrtz(r2.x, r2.y), pkrtz(r2.z, r2.w));

#define GLOADB(buf, kss)                                                         \
    {                                                                            \
        _Pragma("unroll")                                                        \
        for (int h = 0; h < 2; ++h)                                              \
            _Pragma("unroll")                                                    \
            for (int rr = 0; rr < 2; ++rr)                                       \
                gload16(wsB + (size_t)(2 * (kss) + h) * 32768 +                  \
                            (size_t)nb * 64 + rr * 8192 + tid * 16,              \
                        Bs[buf] + h * 16384 + rr * 8192 + tid * 16);             \
    }

#define COMPUTE(buf)                                                             \
    {                                                                            \
        _Pragma("unroll")                                                        \
        for (int kh = 0; kh < 2; ++kh) {                                         \
            const uint32_t kc = (uint32_t)(l >> 4);                              \
            f16x8 af[4], bf[2];                                                  \
            _Pragma("unroll")                                                    \
            for (int mf = 0; mf < 4; ++mf) {                                     \
                const int row = mf * 16 + (l & 15);                              \
                af[mf] = *(const f16x8*)(As[buf] + kh * 4096 + row * 64 +        \
                                         ((kc ^ ((row >> 1) & 3)) << 4));        \
            }                                                                    \
            _Pragma("unroll")                                                    \
            for (int nf = 0; nf < 2; ++nf) {                                     \
                const int row = w * 32 + nf * 16 + (l & 15);                     \
                bf[nf] = *(const f16x8*)(Bs[buf] + kh * 16384 + row * 64 +       \
                                         ((kc ^ ((row >> 1) & 3)) << 4));        \
            }                                                                    \
            _Pragma("unroll")                                                    \
            for (int mf = 0; mf < 4; ++mf)                                       \
                _Pragma("unroll")                                                \
                for (int nf = 0; nf < 2; ++nf)                                   \
                    acc[mf][nf] = __builtin_amdgcn_mfma_f32_16x16x32_f16(        \
                        af[mf], bf[nf], acc[mf][nf], 0, 0, 0);                   \
        }                                                                        \
    }

    // ---- prologue: establish Bs[0]/As[0], v(1) in va, v(2) in vb ----
    GLOADB(0, 0);
    FENCE();
    LOADV(va1, va2, 0);
    asm volatile("s_waitcnt vmcnt(0)" ::: "memory");
    CVTWRITE(0, va1, va2);
    LOADV(va1, va2, 1);
    LOADV(vb1, vb2, 2);
    asm volatile("s_waitcnt lgkmcnt(0)" ::: "memory");
    __builtin_amdgcn_s_barrier();

    // ---- main loop ----
#pragma unroll 2
    for (int ks = 0; ks < KS - 1; ++ks) {
        const int cur = ks & 1, nxt = cur ^ 1;
        GLOADB(nxt, ks + 1);                        // oldest vmem of this iter
        FENCE();                                    // pin issue order
        COMPUTE(cur);
        CVTWRITE(nxt, va1, va2);                    // compiler waits v regs
        {
            const int kload = (ks + 3 < KS) ? ks + 3 : KS - 1;
            LOADV(va1, va2, kload);                 // newest vmem of this iter
        }
        { float4 t1 = va1, t2 = va2; va1 = vb1; va2 = vb2; vb1 = t1; vb2 = t2; }
        asm volatile("s_waitcnt vmcnt(2) lgkmcnt(0)" ::: "memory");
        __builtin_amdgcn_s_barrier();
    }
    COMPUTE((KS - 1) & 1);

    // ---- epilogue: y = acc + bias ----
#pragma unroll
    for (int nf = 0; nf < 2; ++nf) {
        const int n = nb + w * 32 + nf * 16 + (l & 15);
        const float bv = bias[n];
#pragma unroll
        for (int mf = 0; mf < 4; ++mf) {
            const int m0 = mb + mf * 16 + ((l >> 4) << 2);
#pragma unroll
            for (int r = 0; r < 4; ++r)
                y[(size_t)(m0 + r) * UNITS + n] = acc[mf][nf][r] + bv;
        }
    }
#undef LOADV
#undef CVTWRITE
#undef GLOADB
#undef COMPUTE
}

extern "C" void kernel_launch(void* const* d_in, const int* in_sizes, int n_in,
                              void* d_out, int out_size, void* d_ws, size_t ws_size,
                              hipStream_t stream) {
    const float* x  = (const float*)d_in[0];   // [16384,1024]
    const float* W  = (const float*)d_in[1];   // [512,1024]
    const float* bv = (const float*)d_in[2];   // [512]
    const float* D  = (const float*)d_in[3];   // [512,1024]
    const float* GN = (const float*)d_in[4];   // [1,512,1024]
    float* y = (float*)d_out;                  // [16384,512]

    char* wsB = (char*)d_ws;                   // 32 blocks x 32 KB = 1 MB

    topk_pack<<<UNITS, 64, 0, stream>>>(D, GN, W, wsB);
    gemm_kernel<<<(BATCH / BM) * (UNITS / BN), NT, 0, stream>>>(x, bv, wsB, y);
}